// Round 1
// baseline (132.140 us; speedup 1.0000x reference)
//
#include <hip/hip_runtime.h>
#include <math.h>

// Second-order IIR (B=1024 rows, T=16384), fp32.
// V3: register-resident data path. Each thread owns one contiguous 32-elem
// chunk (= one 128B line) per half: direct global->VGPR loads, direct
// VGPR->global stores (L2 merges per-lane 16B writes into full lines).
// LDS holds ONLY the 256 chunk states (2 KB) for the wave-0 affine scan.
// Raw s_barrier + lgkmcnt-only waits: global loads/stores stay in flight
// across barriers (no vmcnt(0) drain), half-1 u prefetched into regs
// before half-0's scan barriers.

#define TLEN  16384
#define HALF  8192
#define NT    256
#define CK    32
#define NCH   256                 // chunks per half (== NT)
#define CARRY_OFF (2*NCH)         // carry slot after state array
#define LDS_FLOATS (2*NCH + 2)    // 514 floats = 2056 B

__device__ __forceinline__ void mat2_sq(float& m00, float& m01, float& m10, float& m11) {
    float t00 = m00*m00 + m01*m10;
    float t01 = m00*m01 + m01*m11;
    float t10 = m10*m00 + m11*m10;
    float t11 = m10*m01 + m11*m11;
    m00 = t00; m01 = t01; m10 = t10; m11 = t11;
}

// Raw barrier: orders LDS (lgkm) across the workgroup but does NOT drain
// vmcnt -> outstanding global loads/stores survive the barrier.
__device__ __forceinline__ void bar_lgkm() {
    asm volatile("s_waitcnt lgkmcnt(0)" ::: "memory");
    __builtin_amdgcn_s_barrier();
    __builtin_amdgcn_sched_barrier(0);
}

__global__ __launch_bounds__(NT, 4)
void iir_kernel(const float* __restrict__ bc,
                const float* __restrict__ rho_p,
                const float* __restrict__ psi_p,
                const float* __restrict__ u_in,
                const float* __restrict__ y_init,
                const float* __restrict__ u_init,
                float* __restrict__ y_out)
{
    __shared__ float lds[LDS_FLOATS];
    const int row = blockIdx.x;
    const int tid = threadIdx.x;

    const float* urow = u_in  + (size_t)row * TLEN;
    float*       orow = y_out + (size_t)row * TLEN;

    // ---- issue half-0 loads immediately (1 line per lane + 8B history) ----
    float4 uv[8];
    {
        const float4* up = (const float4*)(urow + CK * tid);
        #pragma unroll
        for (int j = 0; j < 8; ++j) uv[j] = up[j];
    }
    float hm2, hm1;                       // u[start-2], u[start-1]
    if (tid == 0) {
        hm2 = u_init[2*row + 1];          // u_ext[0] = u_init[:,1]
        hm1 = u_init[2*row + 0];          // u_ext[1] = u_init[:,0]
    } else {
        float2 hh = *(const float2*)(urow + CK*tid - 2);
        hm2 = hh.x; hm1 = hh.y;
    }

    // scalar filter parameters (cheap, per-thread; same math as before)
    const float rho = rho_p[0];
    const float psi = psi_p[0];
    const float r   = 1.0f / (1.0f + expf(-rho));
    const float th  = 3.14159265358979323846f / (1.0f + expf(-psi));
    const float a1  = -2.0f * r * cosf(th);
    const float a2  = r * r;
    const float b0  = bc[0], b1 = bc[1], b2 = bc[2];

    float v[CK];

    #pragma unroll
    for (int h = 0; h < 2; ++h) {
        // ---- pass 1: zero-state chunk response, v kept in VGPRs ----
        float um2 = hm2, um1 = hm1;
        float y1 = 0.0f, y2 = 0.0f;
        #define STEP(UC, IDX) {                                        \
            float uc_ = (UC);                                          \
            float vv_ = fmaf(b2, um2, fmaf(b1, um1, b0 * uc_));        \
            v[IDX] = vv_;                                              \
            float y_ = fmaf(-a1, y1, fmaf(-a2, y2, vv_));              \
            y2 = y1; y1 = y_;                                          \
            um2 = um1; um1 = uc_; }
        #pragma unroll
        for (int q = 0; q < 8; ++q) {
            float4 u4 = uv[q];
            STEP(u4.x, 4*q + 0);
            STEP(u4.y, 4*q + 1);
            STEP(u4.z, 4*q + 2);
            STEP(u4.w, 4*q + 3);
        }
        #undef STEP

        // chunk state d = (y[last], y[last-1])
        *(float2*)&lds[2*tid] = make_float2(y1, y2);

        // ---- prefetch half 1 into regs BEFORE the barriers: the loads
        //      stay in flight across scan + pass3 (raw barriers, no vmcnt drain)
        if (h == 0) {
            const float4* up = (const float4*)(urow + HALF + CK * tid);
            #pragma unroll
            for (int j = 0; j < 8; ++j) uv[j] = up[j];
            float2 hh = *(const float2*)(urow + HALF + CK*tid - 2); // tid0: urow[HALF-2]
            hm2 = hh.x; hm1 = hh.y;
        }

        bar_lgkm();                       // states visible

        // ---- wave-0 affine scan over 256 chunk states ----
        if (tid < 64) {
            const int l = tid;
            // M = A^CK = A^32 via 5 squarings; A = [[-a1,-a2],[1,0]]
            float m00 = -a1, m01 = -a2, m10 = 1.0f, m11 = 0.0f;
            #pragma unroll
            for (int s = 0; s < 5; ++s) mat2_sq(m00, m01, m10, m11);

            float4 q0 = *(const float4*)&lds[8*l];      // chunks 4l, 4l+1
            float4 q1 = *(const float4*)&lds[8*l + 4];  // chunks 4l+2, 4l+3
            float da[4] = {q0.x, q0.z, q1.x, q1.z};
            float db[4] = {q0.y, q0.w, q1.y, q1.w};

            float seed0 = 0.0f, seed1 = 0.0f;
            if (l == 0) {
                if (h == 0) { seed0 = y_init[2*row]; seed1 = y_init[2*row + 1]; }
                else        { seed0 = lds[CARRY_OFF]; seed1 = lds[CARRY_OFF + 1]; }
            }
            // serial fold of this lane's 4 chunks (lane 0 seeded with s_{-1})
            float s0 = seed0, s1 = seed1;
            #pragma unroll
            for (int m = 0; m < 4; ++m) {
                float n0 = fmaf(m00, s0, fmaf(m01, s1, da[m]));
                float n1 = fmaf(m10, s0, fmaf(m11, s1, db[m]));
                s0 = n0; s1 = n1;
            }
            // W = M^4; Kogge-Stone inclusive scan over 64 lanes
            float w00 = m00, w01 = m01, w10 = m10, w11 = m11;
            mat2_sq(w00, w01, w10, w11);
            mat2_sq(w00, w01, w10, w11);
            #pragma unroll
            for (int p = 0; p < 6; ++p) {
                float o0 = __shfl_up(s0, 1 << p);
                float o1 = __shfl_up(s1, 1 << p);
                if (l >= (1 << p)) {
                    s0 = fmaf(w00, o0, fmaf(w01, o1, s0));
                    s1 = fmaf(w10, o0, fmaf(w11, o1, s1));
                }
                if (p < 5) mat2_sq(w00, w01, w10, w11);
            }
            // incoming state for chunk 4l = prefix of lane l-1 (or seed for l=0)
            float p0 = __shfl_up(s0, 1);
            float p1 = __shfl_up(s1, 1);
            if (l == 0) { p0 = seed0; p1 = seed1; }
            float c0 = p0, c1 = p1;
            #pragma unroll
            for (int m = 0; m < 4; ++m) {
                *(float2*)&lds[2*(4*l + m)] = make_float2(c0, c1);
                float n0 = fmaf(m00, c0, fmaf(m01, c1, da[m]));
                float n1 = fmaf(m10, c0, fmaf(m11, c1, db[m]));
                c0 = n0; c1 = n1;
            }
            if (l == 63 && h == 0) {      // exact carry into half 1 (outgoing of chunk 255)
                lds[CARRY_OFF]     = c0;
                lds[CARRY_OFF + 1] = c1;
            }
        }
        bar_lgkm();

        // ---- pass 3: exact recurrence from incoming state, direct store ----
        float2 inc = *(const float2*)&lds[2*tid];
        float y1f = inc.x, y2f = inc.y;
        float* oh = orow + h * HALF + CK * tid;
        #pragma unroll
        for (int q = 0; q < 8; ++q) {
            float ya = fmaf(-a1, y1f, fmaf(-a2, y2f, v[4*q + 0]));
            float yb = fmaf(-a1, ya,  fmaf(-a2, y1f, v[4*q + 1]));
            float yc = fmaf(-a1, yb,  fmaf(-a2, ya,  v[4*q + 2]));
            float yd = fmaf(-a1, yc,  fmaf(-a2, yb,  v[4*q + 3]));
            float4 w; w.x = ya; w.y = yb; w.z = yc; w.w = yd;
            *(float4*)(oh + 4*q) = w;     // per-lane contiguous 128B; L2 merges
            y2f = yc; y1f = yd;
        }
        if (h == 0) bar_lgkm();           // protect scan array before half-1 state writes
    }
}

extern "C" void kernel_launch(void* const* d_in, const int* in_sizes, int n_in,
                              void* d_out, int out_size, void* d_ws, size_t ws_size,
                              hipStream_t stream) {
    const float* bc    = (const float*)d_in[0];
    const float* rho   = (const float*)d_in[1];
    const float* psi   = (const float*)d_in[2];
    const float* u_in  = (const float*)d_in[3];
    const float* y_in  = (const float*)d_in[4];
    const float* u_ini = (const float*)d_in[5];
    float* y = (float*)d_out;
    const int B = in_sizes[3] / TLEN;     // 1024
    iir_kernel<<<B, NT, 0, stream>>>(bc, rho, psi, u_in, y_in, u_ini, y);
}